// Round 5
// baseline (78.702 us; speedup 1.0000x reference)
//
#include <hip/hip_runtime.h>

#define LN_EPS 1e-5f
#define TS 36            // LDS tile row stride in floats (144B, 16B-aligned)
#define TILE (32 * TS)   // one 32x32 tile with padding

__device__ __forceinline__ void wave_reduce2(float& s1, float& s2) {
  #pragma unroll
  for (int off = 32; off; off >>= 1) {
    s1 += __shfl_xor(s1, off);
    s2 += __shfl_xor(s2, off);
  }
}

__device__ __forceinline__ void ld_tile_regs(float x[4][4],
                                             const float* __restrict__ src,
                                             int i0, int j0) {
  #pragma unroll
  for (int rr = 0; rr < 4; ++rr)
    *(float4*)x[rr] = *(const float4*)&src[(i0 + rr) * 32 + j0];
}

__device__ __forceinline__ void wr_transp(float* dst, const float acc[4][4],
                                          int i0, int j0) {
  #pragma unroll
  for (int cc = 0; cc < 4; ++cc) {
    float4 w = make_float4(acc[0][cc], acc[1][cc], acc[2][cc], acc[3][cc]);
    *(float4*)&dst[(j0 + cc) * TS + i0] = w;
  }
}

__device__ __forceinline__ void wr_norm(float* dst, const float acc[4][4],
                                        int i0, int j0) {
  #pragma unroll
  for (int rr = 0; rr < 4; ++rr) {
    float4 w = make_float4(acc[rr][0], acc[rr][1], acc[rr][2], acc[rr][3]);
    *(float4*)&dst[(i0 + rr) * TS + j0] = w;
  }
}

// stage a 32x32 row-major global tile into LDS [32][TS], optionally transposed
__device__ __forceinline__ void stage_tile(float* dst,
                                           const float* __restrict__ src,
                                           int i0, int j0, bool transp) {
  float x[4][4];
  ld_tile_regs(x, src, i0, j0);
  if (transp) wr_transp(dst, x, i0, j0);
  else wr_norm(dst, x, i0, j0);
}

// acc(4x4) = A @ B ; At = A transposed in LDS (At[k][i]), Bn normal (B[k][j])
__device__ __forceinline__ void mm4x4(const float* At, const float* Bn,
                                      int i0, int j0, float acc[4][4]) {
  #pragma unroll
  for (int ii = 0; ii < 4; ++ii)
    #pragma unroll
    for (int jj = 0; jj < 4; ++jj) acc[ii][jj] = 0.f;
  #pragma unroll 8
  for (int k = 0; k < 32; ++k) {
    float4 av = *(const float4*)&At[k * TS + i0];
    float4 bv = *(const float4*)&Bn[k * TS + j0];
    const float* ap = (const float*)&av;
    const float* bp = (const float*)&bv;
    #pragma unroll
    for (int ii = 0; ii < 4; ++ii)
      #pragma unroll
      for (int jj = 0; jj < 4; ++jj)
        acc[ii][jj] = fmaf(ap[ii], bp[jj], acc[ii][jj]);
  }
}

// Full tree node on ONE wave. Lt = left child transposed, Rn = right normal,
// Cn = emb normal. h = relu(LN((L@R@C)@Ww^T + Wb)) -> written into Cn slot.
// T1^T trashes Lt, T2^T trashes Rn. In-wave LDS ordering makes this safe.
__device__ __forceinline__ void node_wave(float* Lt, float* Rn, float* Cn,
                                          const float* Wwt, int i0, int j0,
                                          const float4 wbv, const float g[4][4],
                                          const float be[4][4], bool transpOut) {
  float acc[4][4];
  mm4x4(Lt, Rn, i0, j0, acc);
  wr_transp(Lt, acc, i0, j0);           // T1^T
  mm4x4(Lt, Cn, i0, j0, acc);
  wr_transp(Rn, acc, i0, j0);           // T2^T
  mm4x4(Rn, Wwt, i0, j0, acc);
  const float* wbp = (const float*)&wbv;
  float s1 = 0.f, s2 = 0.f;
  #pragma unroll
  for (int ii = 0; ii < 4; ++ii)
    #pragma unroll
    for (int jj = 0; jj < 4; ++jj) {
      acc[ii][jj] += wbp[jj];
      s1 += acc[ii][jj];
      s2 += acc[ii][jj] * acc[ii][jj];
    }
  wave_reduce2(s1, s2);
  const float mu = s1 * (1.0f / 1024.0f);
  const float rs = rsqrtf(s2 * (1.0f / 1024.0f) - mu * mu + LN_EPS);
  #pragma unroll
  for (int ii = 0; ii < 4; ++ii)
    #pragma unroll
    for (int jj = 0; jj < 4; ++jj)
      acc[ii][jj] = fmaxf((acc[ii][jj] - mu) * rs * g[ii][jj] + be[ii][jj], 0.f);
  if (transpOut) wr_transp(Cn, acc, i0, j0);
  else wr_norm(Cn, acc, i0, j0);
}

// ---- device-scope dataflow flags ----
__device__ __forceinline__ void flag_wait(const unsigned* f) {
  while (__hip_atomic_load(f, __ATOMIC_RELAXED, __HIP_MEMORY_SCOPE_AGENT) == 0u)
    __builtin_amdgcn_s_sleep(2);
}

// Three tree levels (4 -> 2 -> 1 nodes) from hin (8 tiles) to hout (1 tile).
// Word-id bases: b0 (4-node level), b1 (2-node), b2 (1-node).
__device__ __forceinline__ void phase3(
    int blk, int u, int wv, int i0, int j0,
    const float* __restrict__ hin, const unsigned* __restrict__ fin,
    float* __restrict__ hout, unsigned* __restrict__ fout,
    int b0, int b1, int b2,
    const int* __restrict__ word_ids, const float* __restrict__ emb,
    float* pool, const float4 wbv, const float g[4][4], const float be[4][4]) {
  // independent emb loads first (hide under flag wait)
  stage_tile(pool + (8 + wv) * TILE,
             emb + (size_t)word_ids[b0 + 4 * blk + wv] * 1024, i0, j0, false);
  float pf[4][4];
  const bool havepf = wv < 3;
  if (havepf) {
    const int pid = (wv == 2) ? (b2 + blk) : (b1 + 2 * blk + wv);
    ld_tile_regs(pf, emb + (size_t)word_ids[pid] * 1024, i0, j0);
  }
  // wait for the 8 producer tiles
  if (u < 8) flag_wait(fin + 8 * blk + u);
  __syncthreads();
  __threadfence();   // acquire: invalidate caches before reading hin
  // stage children: wave w -> slots 2w (transposed, left) and 2w+1 (normal)
  stage_tile(pool + (2 * wv) * TILE, hin + (size_t)(8 * blk + 2 * wv) * 1024,
             i0, j0, true);
  stage_tile(pool + (2 * wv + 1) * TILE,
             hin + (size_t)(8 * blk + 2 * wv + 1) * 1024, i0, j0, false);
  __syncthreads();
  // level A: 4 nodes, one per wave; m even -> left child -> transposed out
  node_wave(pool + (2 * wv) * TILE, pool + (2 * wv + 1) * TILE,
            pool + (8 + wv) * TILE, pool + 12 * TILE, i0, j0, wbv, g, be,
            (wv & 1) == 0);
  __syncthreads();
  // dump prefetched C tiles for levels B and C into dead slots 0,1,2
  if (havepf) wr_norm(pool + wv * TILE, pf, i0, j0);
  __syncthreads();
  // level B: 2 nodes on waves 0,1; q=0 left -> transposed
  if (wv < 2)
    node_wave(pool + (8 + 2 * wv) * TILE, pool + (9 + 2 * wv) * TILE,
              pool + wv * TILE, pool + 12 * TILE, i0, j0, wbv, g, be, wv == 0);
  __syncthreads();
  // level C: 1 node on wave 0; output normal into slot 2
  if (wv == 0)
    node_wave(pool + 0, pool + TILE, pool + 2 * TILE, pool + 12 * TILE, i0, j0,
              wbv, g, be, false);
  __syncthreads();
  {
    const int r = u >> 3, c = (u & 7) * 4;
    *(float4*)&hout[(size_t)blk * 1024 + r * 32 + c] =
        *(float4*)&pool[2 * TILE + r * TS + c];
  }
  __syncthreads();
  __threadfence();   // release: write back before flag
  if (u == 0)
    __hip_atomic_store(fout + blk, 1u, __ATOMIC_RELAXED, __HIP_MEMORY_SCOPE_AGENT);
}

// ---- the whole tree in one kernel ----
__global__ __launch_bounds__(256) void k_tree(
    const int* __restrict__ word_ids, const float* __restrict__ emb,
    const float* __restrict__ Ww, const float* __restrict__ Wb,
    const float* __restrict__ gamma, const float* __restrict__ beta,
    const float* __restrict__ Pw, const float* __restrict__ Pb,
    const int* __restrict__ label,
    float* __restrict__ h8, float* __restrict__ h5, float* __restrict__ h2,
    unsigned* __restrict__ h8f, unsigned* __restrict__ h5f,
    unsigned* __restrict__ h2f, float* __restrict__ out) {
  __shared__ float pool[13 * TILE];   // slots 0..11 work, 12 = Ww^T (permanent)
  const int u = threadIdx.x, blk = blockIdx.x;
  const int wv = u >> 6, ln = u & 63;
  const int i0 = (ln >> 3) * 4, j0 = (ln & 7) * 4;

  float g[4][4], be[4][4];
  #pragma unroll
  for (int rr = 0; rr < 4; ++rr) {
    *(float4*)g[rr] = *(const float4*)&gamma[(i0 + rr) * 32 + j0];
    *(float4*)be[rr] = *(const float4*)&beta[(i0 + rr) * 32 + j0];
  }
  const float4 wbv = *(const float4*)&Wb[j0];

  // ---- bottom: leaves + L9 + L8 (every block) ----
  {
    // leaf loads first
    float x[4][4];
    const int wid = word_ids[1023 + 4 * blk + wv];
    ld_tile_regs(x, emb + (size_t)wid * 1024, i0, j0);
    // role staging: C(L9A)->2, C(L9B)->5, C(L8)->6, Ww^T->12
    if (wv == 0)
      stage_tile(pool + 2 * TILE, emb + (size_t)word_ids[511 + 2 * blk] * 1024, i0, j0, false);
    else if (wv == 1)
      stage_tile(pool + 5 * TILE, emb + (size_t)word_ids[511 + 2 * blk + 1] * 1024, i0, j0, false);
    else if (wv == 2)
      stage_tile(pool + 6 * TILE, emb + (size_t)word_ids[255 + blk] * 1024, i0, j0, false);
    else
      stage_tile(pool + 12 * TILE, Ww, i0, j0, true);
    // leaf LN in registers
    float s1 = 0.f, s2 = 0.f;
    #pragma unroll
    for (int rr = 0; rr < 4; ++rr)
      #pragma unroll
      for (int cc = 0; cc < 4; ++cc) { s1 += x[rr][cc]; s2 += x[rr][cc] * x[rr][cc]; }
    wave_reduce2(s1, s2);
    const float mu = s1 * (1.0f / 1024.0f);
    const float rs = rsqrtf(s2 * (1.0f / 1024.0f) - mu * mu + LN_EPS);
    #pragma unroll
    for (int rr = 0; rr < 4; ++rr)
      #pragma unroll
      for (int cc = 0; cc < 4; ++cc)
        x[rr][cc] = fmaxf((x[rr][cc] - mu) * rs * g[rr][cc] + be[rr][cc], 0.f);
    const int slot = (wv < 2) ? wv : wv + 1;   // 0,1,3,4
    if ((wv & 1) == 0) wr_transp(pool + slot * TILE, x, i0, j0);  // odd idx = left
    else wr_norm(pool + slot * TILE, x, i0, j0);
    __syncthreads();
    // L9: wave 0 -> node A (out transposed, slot 2), wave 1 -> node B (slot 5)
    if (wv < 2)
      node_wave(pool + (3 * wv) * TILE, pool + (3 * wv + 1) * TILE,
                pool + (3 * wv + 2) * TILE, pool + 12 * TILE, i0, j0, wbv, g, be,
                wv == 0);
    __syncthreads();
    // L8: wave 0: Lt=2, Rn=5, Cn=6 -> normal out in 6
    if (wv == 0)
      node_wave(pool + 2 * TILE, pool + 5 * TILE, pool + 6 * TILE,
                pool + 12 * TILE, i0, j0, wbv, g, be, false);
    __syncthreads();
    {
      const int r = u >> 3, c = (u & 7) * 4;
      *(float4*)&h8[(size_t)blk * 1024 + r * 32 + c] =
          *(float4*)&pool[6 * TILE + r * TS + c];
    }
    __syncthreads();
    __threadfence();
    if (u == 0)
      __hip_atomic_store(h8f + blk, 1u, __ATOMIC_RELAXED, __HIP_MEMORY_SCOPE_AGENT);
  }

  if (blk >= 32) return;
  // ---- P2: L7,L6,L5 on blocks 0..31 ----
  phase3(blk, u, wv, i0, j0, h8, h8f, h5, h5f, 127, 63, 31, word_ids, emb, pool,
         wbv, g, be);

  if (blk >= 4) return;
  // ---- P3: L4,L3,L2 on blocks 0..3 ----
  phase3(blk, u, wv, i0, j0, h5, h5f, h2, h2f, 15, 7, 3, word_ids, emb, pool,
         wbv, g, be);

  if (blk >= 1) return;
  // ---- P4: L1, L0 + head on block 0 ----
  {
    // independent emb loads first
    if (wv == 0)
      stage_tile(pool + 4 * TILE, emb + (size_t)word_ids[1] * 1024, i0, j0, false);
    else if (wv == 1)
      stage_tile(pool + 5 * TILE, emb + (size_t)word_ids[2] * 1024, i0, j0, false);
    else if (wv == 2)
      stage_tile(pool + 6 * TILE, emb + (size_t)word_ids[0] * 1024, i0, j0, false);
    if (u < 4) flag_wait(h2f + u);
    __syncthreads();
    __threadfence();
    // children h2[0..3] -> slots 0..3 (even position = left = transposed)
    stage_tile(pool + wv * TILE, h2 + (size_t)wv * 1024, i0, j0, (wv & 1) == 0);
    __syncthreads();
    // L1: waves 0,1; n1=1 (left) -> transposed out
    if (wv < 2)
      node_wave(pool + (2 * wv) * TILE, pool + (2 * wv + 1) * TILE,
                pool + (4 + wv) * TILE, pool + 12 * TILE, i0, j0, wbv, g, be,
                wv == 0);
    __syncthreads();
    // L0: wave 0: Lt=4, Rn=5, Cn=6 -> normal out in 6
    if (wv == 0)
      node_wave(pool + 4 * TILE, pool + 5 * TILE, pool + 6 * TILE,
                pool + 12 * TILE, i0, j0, wbv, g, be, false);
    __syncthreads();
    // head from slot 6 (root, normal layout)
    if (wv == 0) {
      float logits[10];
      #pragma unroll
      for (int c = 0; c < 10; ++c) {
        float p = 0.f;
        #pragma unroll
        for (int q = 0; q < 16; ++q) {
          const int e = q * 64 + ln;
          const int r = e >> 5, cc = e & 31;
          p += pool[6 * TILE + r * TS + cc] * Pw[c * 1024 + e];
        }
        #pragma unroll
        for (int off = 32; off; off >>= 1) p += __shfl_xor(p, off);
        logits[c] = p + Pb[c];
      }
      if (u == 0) {
        float mmax = logits[0];
        int am = 0;
        #pragma unroll
        for (int c = 1; c < 10; ++c)
          if (logits[c] > mmax) { mmax = logits[c]; am = c; }
        float sum = 0.f;
        #pragma unroll
        for (int c = 0; c < 10; ++c) sum += expf(logits[c] - mmax);
        float loss = -(logits[label[0]] - mmax - logf(sum));
        out[0] = (float)am;
        out[1] = loss;
      }
    }
  }
}

extern "C" void kernel_launch(void* const* d_in, const int* in_sizes, int n_in,
                              void* d_out, int out_size, void* d_ws, size_t ws_size,
                              hipStream_t stream) {
  const int* word_ids = (const int*)d_in[0];
  const int* label = (const int*)d_in[1];
  const float* emb = (const float*)d_in[2];
  const float* Ww = (const float*)d_in[3];
  const float* Wb = (const float*)d_in[4];
  const float* g = (const float*)d_in[5];
  const float* b = (const float*)d_in[6];
  const float* Pw = (const float*)d_in[7];
  const float* Pb = (const float*)d_in[8];
  float* out = (float*)d_out;

  float* h8 = (float*)d_ws;           // 256 tiles
  float* h5 = h8 + 256 * 1024;        // 32 tiles
  float* h2 = h5 + 32 * 1024;         // 4 tiles
  unsigned* flags = (unsigned*)(h2 + 4 * 1024);
  unsigned* h8f = flags;              // 256
  unsigned* h5f = flags + 256;        // 32
  unsigned* h2f = flags + 288;        // 4

  hipMemsetAsync(flags, 0, 292 * sizeof(unsigned), stream);
  k_tree<<<256, 256, 0, stream>>>(word_ids, emb, Ww, Wb, g, b, Pw, Pb, label,
                                  h8, h5, h2, h8f, h5f, h2f, out);
}

// Round 6
// 30.823 us; speedup vs baseline: 2.5534x; 2.5534x over previous
//
#include <hip/hip_runtime.h>
#include <hip/hip_bf16.h>

#define LN_EPS 1e-5f
#define TSB 40                 // LDS tile row stride in bf16 (80B, 16B-aligned)
#define TILEB (32 * TSB)       // shorts per tile

typedef __attribute__((ext_vector_type(8))) short bf16x8;
typedef __attribute__((ext_vector_type(16))) float f32x16;

__device__ __forceinline__ short bf16b(float f) {
  return __builtin_bit_cast(short, __float2bfloat16(f));
}

__device__ __forceinline__ void wave_reduce2(float& s1, float& s2) {
  #pragma unroll
  for (int off = 32; off; off >>= 1) {
    s1 += __shfl_xor(s1, off);
    s2 += __shfl_xor(s2, off);
  }
}

// A-frag/B-frag read from a row-major-[32][TSB] LDS tile.
// For A (normal tile): lane m=l&31 holds A[m][k], k=(l>>5)*8+i (+k0).
// For B (transposed tile Bt[n][k]): lane n=l&31 holds B[k][n] likewise.
__device__ __forceinline__ bf16x8 frag_ld(const short* t, int l, int k0) {
  return *(const bf16x8*)&t[(l & 31) * TSB + ((l >> 5) << 3) + k0];
}

__device__ __forceinline__ int cd_row(int r, int l) {
  return (r & 3) + 8 * (r >> 2) + 4 * (l >> 5);   // verified C/D mapping
}

__device__ __forceinline__ void cd_store(short* t, int l, const f32x16 d,
                                         bool transp) {
  const int col = l & 31;
  if (transp) {
    #pragma unroll
    for (int r = 0; r < 16; ++r) t[col * TSB + cd_row(r, l)] = bf16b(d[r]);
  } else {
    #pragma unroll
    for (int r = 0; r < 16; ++r) t[cd_row(r, l) * TSB + col] = bf16b(d[r]);
  }
}

struct NodeParams {
  bf16x8 w0, w1;        // Ww^T B-fragments (k0=0,16)
  float wb;             // Wb[col]
  float ga[16], be[16]; // gamma/beta at this lane's 16 C/D positions
};

__device__ __forceinline__ NodeParams load_params(const float* __restrict__ Ww,
    const float* __restrict__ Wb, const float* __restrict__ gamma,
    const float* __restrict__ beta, int l) {
  NodeParams P;
  const int n = l & 31, kh = (l >> 5) * 8;
  float w[8];
  *(float4*)&w[0] = *(const float4*)&Ww[n * 32 + kh];
  *(float4*)&w[4] = *(const float4*)&Ww[n * 32 + kh + 4];
  #pragma unroll
  for (int i = 0; i < 8; ++i) P.w0[i] = bf16b(w[i]);
  *(float4*)&w[0] = *(const float4*)&Ww[n * 32 + kh + 16];
  *(float4*)&w[4] = *(const float4*)&Ww[n * 32 + kh + 20];
  #pragma unroll
  for (int i = 0; i < 8; ++i) P.w1[i] = bf16b(w[i]);
  P.wb = Wb[n];
  #pragma unroll
  for (int r = 0; r < 16; ++r) {
    const int idx = cd_row(r, l) * 32 + n;
    P.ga[r] = gamma[idx];
    P.be[r] = beta[idx];
  }
  return P;
}

__device__ __forceinline__ f32x16 mm32(const short* A, const short* B, int l) {
  f32x16 acc = {};
  acc = __builtin_amdgcn_mfma_f32_32x32x16_bf16(frag_ld(A, l, 0),
                                                frag_ld(B, l, 0), acc, 0, 0, 0);
  acc = __builtin_amdgcn_mfma_f32_32x32x16_bf16(frag_ld(A, l, 16),
                                                frag_ld(B, l, 16), acc, 0, 0, 0);
  return acc;
}

// Full tree node on ONE wave. A = left child (normal), Bt = right child
// (transposed), Ct = emb C (transposed). T1 scratch -> A slot, T2 -> Bt slot
// (same-wave in-order LDS). Output h: fp32 to fout (root) or bf16 to dst.
__device__ __forceinline__ void node_mfma(short* A, short* Bt, const short* Ct,
                                          const NodeParams& P, int l,
                                          short* dst, bool transpOut,
                                          float* fout) {
  f32x16 t1 = mm32(A, Bt, l);
  cd_store(A, l, t1, false);            // T1 (normal) into A slot
  f32x16 t2 = mm32(A, Ct, l);
  cd_store(Bt, l, t2, false);           // T2 (normal) into Bt slot
  f32x16 x = {};
  x = __builtin_amdgcn_mfma_f32_32x32x16_bf16(frag_ld(Bt, l, 0), P.w0, x, 0, 0, 0);
  x = __builtin_amdgcn_mfma_f32_32x32x16_bf16(frag_ld(Bt, l, 16), P.w1, x, 0, 0, 0);
  float s1 = 0.f, s2 = 0.f;
  #pragma unroll
  for (int r = 0; r < 16; ++r) {
    x[r] += P.wb;
    s1 += x[r];
    s2 += x[r] * x[r];
  }
  wave_reduce2(s1, s2);
  const float mu = s1 * (1.f / 1024.f);
  const float rs = rsqrtf(s2 * (1.f / 1024.f) - mu * mu + LN_EPS);
  #pragma unroll
  for (int r = 0; r < 16; ++r)
    x[r] = fmaxf((x[r] - mu) * rs * P.ga[r] + P.be[r], 0.f);
  if (fout) {
    #pragma unroll
    for (int r = 0; r < 16; ++r) fout[cd_row(r, l) * 32 + (l & 31)] = x[r];
  } else {
    cd_store(dst, l, x, transpOut);
  }
}

// fp32 global tile [32][32] -> LDS bf16, normal or transposed; one wave
__device__ __forceinline__ void stage_f32(short* dst,
                                          const float* __restrict__ src, int l,
                                          bool transp) {
  float v[16];
  #pragma unroll
  for (int q = 0; q < 4; ++q)
    *(float4*)&v[q * 4] = *(const float4*)&src[l * 16 + q * 4];
  const int row = l >> 1, c0 = (l & 1) * 16;
  if (transp) {
    #pragma unroll
    for (int i = 0; i < 16; ++i) dst[(c0 + i) * TSB + row] = bf16b(v[i]);
  } else {
    #pragma unroll
    for (int i = 0; i < 8; ++i) {
      unsigned lo = (unsigned short)bf16b(v[2 * i]);
      unsigned hi = (unsigned short)bf16b(v[2 * i + 1]);
      ((unsigned*)dst)[row * (TSB / 2) + (c0 >> 1) + i] = lo | (hi << 16);
    }
  }
}

// bf16 global compact tile [32][32] -> LDS, normal or transposed; one wave
__device__ __forceinline__ void stage_bf16(short* dst,
                                           const short* __restrict__ src, int l,
                                           bool transp) {
  short v[16];
  *(bf16x8*)&v[0] = *(const bf16x8*)&src[l * 16];
  *(bf16x8*)&v[8] = *(const bf16x8*)&src[l * 16 + 8];
  const int row = l >> 1, c0 = (l & 1) * 16;
  if (transp) {
    #pragma unroll
    for (int i = 0; i < 16; ++i) dst[(c0 + i) * TSB + row] = v[i];
  } else {
    #pragma unroll
    for (int i = 0; i < 8; ++i) {
      unsigned lo = (unsigned short)v[2 * i];
      unsigned hi = (unsigned short)v[2 * i + 1];
      ((unsigned*)dst)[row * (TSB / 2) + (c0 >> 1) + i] = lo | (hi << 16);
    }
  }
}

// LDS normal tile -> global compact bf16 [32][32]; threads u<128, 1 b128 each
__device__ __forceinline__ void copy_out(short* __restrict__ dst, const short* t,
                                         int u) {
  if (u < 128) {
    const int row = u >> 2, c0 = (u & 3) * 8;
    *(bf16x8*)&dst[row * 32 + c0] = *(const bf16x8*)&t[row * TSB + c0];
  }
}

// leaf: load fp32 tile, LN+ReLU in-wave, write bf16 with parity layout
__device__ __forceinline__ void leaf_ln(short* dst, const float* __restrict__ src,
                                        const float* __restrict__ gamma,
                                        const float* __restrict__ beta, int l,
                                        bool transp) {
  float v[16], ga[16], be[16];
  #pragma unroll
  for (int q = 0; q < 4; ++q) {
    *(float4*)&v[q * 4] = *(const float4*)&src[l * 16 + q * 4];
    *(float4*)&ga[q * 4] = *(const float4*)&gamma[l * 16 + q * 4];
    *(float4*)&be[q * 4] = *(const float4*)&beta[l * 16 + q * 4];
  }
  float s1 = 0.f, s2 = 0.f;
  #pragma unroll
  for (int i = 0; i < 16; ++i) { s1 += v[i]; s2 += v[i] * v[i]; }
  wave_reduce2(s1, s2);
  const float mu = s1 * (1.f / 1024.f);
  const float rs = rsqrtf(s2 * (1.f / 1024.f) - mu * mu + LN_EPS);
  #pragma unroll
  for (int i = 0; i < 16; ++i)
    v[i] = fmaxf((v[i] - mu) * rs * ga[i] + be[i], 0.f);
  const int row = l >> 1, c0 = (l & 1) * 16;
  if (transp) {
    #pragma unroll
    for (int i = 0; i < 16; ++i) dst[(c0 + i) * TSB + row] = bf16b(v[i]);
  } else {
    #pragma unroll
    for (int i = 0; i < 8; ++i) {
      unsigned lo = (unsigned short)bf16b(v[2 * i]);
      unsigned hi = (unsigned short)bf16b(v[2 * i + 1]);
      ((unsigned*)dst)[row * (TSB / 2) + (c0 >> 1) + i] = lo | (hi << 16);
    }
  }
}

// ---- K1: leaves + L9 + L8; 256 blocks x 256 thr ----
__global__ __launch_bounds__(256) void k_bot(
    const int* __restrict__ wid, const float* __restrict__ emb,
    const float* __restrict__ Ww, const float* __restrict__ Wb,
    const float* __restrict__ gamma, const float* __restrict__ beta,
    short* __restrict__ h8) {
  __shared__ __align__(16) short pool[7 * TILEB];
  const int u = threadIdx.x, blk = blockIdx.x;
  const int wv = u >> 6, l = u & 63;
  NodeParams P = load_params(Ww, Wb, gamma, beta, l);
  // C tiles (transposed): L9a->slot4, L9b->slot5, L8->slot6
  if (wv == 0)
    stage_f32(pool + 4 * TILEB, emb + (size_t)wid[511 + 2 * blk] * 1024, l, true);
  else if (wv == 1)
    stage_f32(pool + 5 * TILEB, emb + (size_t)wid[512 + 2 * blk] * 1024, l, true);
  else if (wv == 2)
    stage_f32(pool + 6 * TILEB, emb + (size_t)wid[255 + blk] * 1024, l, true);
  // leaves: one per wave -> slots 0..3; odd position = right = transposed
  leaf_ln(pool + wv * TILEB, emb + (size_t)wid[1023 + 4 * blk + wv] * 1024,
          gamma, beta, l, (wv & 1) != 0);
  __syncthreads();
  // L9 (2 nodes, waves 0,1): out -> C slot; node a left(normal), b right(transp)
  if (wv < 2)
    node_mfma(pool + 2 * wv * TILEB, pool + (2 * wv + 1) * TILEB,
              pool + (4 + wv) * TILEB, P, l, pool + (4 + wv) * TILEB, wv == 1,
              nullptr);
  __syncthreads();
  // L8 (wave 0): out normal -> slot 6
  if (wv == 0)
    node_mfma(pool + 4 * TILEB, pool + 5 * TILEB, pool + 6 * TILEB, P, l,
              pool + 6 * TILEB, false, nullptr);
  __syncthreads();
  copy_out(h8 + (size_t)blk * 1024, pool + 6 * TILEB, u);
}

// ---- K2/K3: three levels (4 -> 2 -> 1 nodes) per block ----
__global__ __launch_bounds__(256) void k_mid(
    const int* __restrict__ wid, const float* __restrict__ emb,
    const float* __restrict__ Ww, const float* __restrict__ Wb,
    const float* __restrict__ gamma, const float* __restrict__ beta,
    const short* __restrict__ hin, short* __restrict__ hout,
    int cb, int pb, int gb) {
  __shared__ __align__(16) short pool[15 * TILEB];
  const int u = threadIdx.x, blk = blockIdx.x;
  const int wv = u >> 6, l = u & 63;
  NodeParams P = load_params(Ww, Wb, gamma, beta, l);
  // children: wave w stages tiles 2w (left,normal) and 2w+1 (right,transposed)
  stage_bf16(pool + 2 * wv * TILEB, hin + (size_t)(8 * blk + 2 * wv) * 1024, l,
             false);
  stage_bf16(pool + (2 * wv + 1) * TILEB,
             hin + (size_t)(8 * blk + 2 * wv + 1) * 1024, l, true);
  // C tiles (transposed): level-A -> slots 8..11; level-B -> 12,13; level-C -> 14
  stage_f32(pool + (8 + wv) * TILEB,
            emb + (size_t)wid[cb + 4 * blk + wv] * 1024, l, true);
  if (wv < 2)
    stage_f32(pool + (12 + wv) * TILEB,
              emb + (size_t)wid[pb + 2 * blk + wv] * 1024, l, true);
  else if (wv == 2)
    stage_f32(pool + 14 * TILEB, emb + (size_t)wid[gb + blk] * 1024, l, true);
  __syncthreads();
  // level A: 4 nodes (one per wave); out -> C slot, parity by wave
  node_mfma(pool + 2 * wv * TILEB, pool + (2 * wv + 1) * TILEB,
            pool + (8 + wv) * TILEB, P, l, pool + (8 + wv) * TILEB,
            (wv & 1) != 0, nullptr);
  __syncthreads();
  // level B: 2 nodes (waves 0,1)
  if (wv < 2)
    node_mfma(pool + (8 + 2 * wv) * TILEB, pool + (9 + 2 * wv) * TILEB,
              pool + (12 + wv) * TILEB, P, l, pool + (12 + wv) * TILEB,
              wv == 1, nullptr);
  __syncthreads();
  // level C: 1 node (wave 0), out normal -> slot 14
  if (wv == 0)
    node_mfma(pool + 12 * TILEB, pool + 13 * TILEB, pool + 14 * TILEB, P, l,
              pool + 14 * TILEB, false, nullptr);
  __syncthreads();
  copy_out(hout + (size_t)blk * 1024, pool + 14 * TILEB, u);
}

// ---- K4: L1 + L0 + head; 1 block ----
__global__ __launch_bounds__(256) void k_top(
    const int* __restrict__ wid, const float* __restrict__ emb,
    const float* __restrict__ Ww, const float* __restrict__ Wb,
    const float* __restrict__ gamma, const float* __restrict__ beta,
    const float* __restrict__ Pw, const float* __restrict__ Pb,
    const int* __restrict__ label, const short* __restrict__ hin,
    float* __restrict__ out) {
  __shared__ __align__(16) short pool[7 * TILEB];
  __shared__ float rootf[1024];
  __shared__ float lred[10];
  const int u = threadIdx.x;
  const int wv = u >> 6, l = u & 63;
  NodeParams P = load_params(Ww, Wb, gamma, beta, l);
  // children h2[0..3] -> slots 0..3 (odd = right = transposed)
  stage_bf16(pool + wv * TILEB, hin + (size_t)wv * 1024, l, (wv & 1) != 0);
  // C tiles: L1a=wid[1]->4, L1b=wid[2]->5, L0=wid[0]->6 (transposed)
  if (wv == 0) stage_f32(pool + 4 * TILEB, emb + (size_t)wid[1] * 1024, l, true);
  else if (wv == 1) stage_f32(pool + 5 * TILEB, emb + (size_t)wid[2] * 1024, l, true);
  else if (wv == 2) stage_f32(pool + 6 * TILEB, emb + (size_t)wid[0] * 1024, l, true);
  __syncthreads();
  // L1: waves 0,1
  if (wv < 2)
    node_mfma(pool + 2 * wv * TILEB, pool + (2 * wv + 1) * TILEB,
              pool + (4 + wv) * TILEB, P, l, pool + (4 + wv) * TILEB, wv == 1,
              nullptr);
  __syncthreads();
  // L0 -> fp32 root
  if (wv == 0)
    node_mfma(pool + 4 * TILEB, pool + 5 * TILEB, pool + 6 * TILEB, P, l,
              nullptr, false, rootf);
  __syncthreads();
  // head: wave wv handles classes c = wv + 4q
  #pragma unroll
  for (int q = 0; q < 3; ++q) {
    const int c = wv + 4 * q;
    if (c < 10) {
      float p = 0.f;
      #pragma unroll
      for (int t = 0; t < 4; ++t) {
        float4 r4 = *(const float4*)&rootf[l * 16 + t * 4];
        float4 w4 = *(const float4*)&Pw[c * 1024 + l * 16 + t * 4];
        p += r4.x * w4.x + r4.y * w4.y + r4.z * w4.z + r4.w * w4.w;
      }
      #pragma unroll
      for (int off = 32; off; off >>= 1) p += __shfl_xor(p, off);
      if (l == 0) lred[c] = p + Pb[c];
    }
  }
  __syncthreads();
  if (u == 0) {
    float mmax = lred[0];
    int am = 0;
    #pragma unroll
    for (int c = 1; c < 10; ++c)
      if (lred[c] > mmax) { mmax = lred[c]; am = c; }
    float sum = 0.f;
    #pragma unroll
    for (int c = 0; c < 10; ++c) sum += expf(lred[c] - mmax);
    const float loss = -(lred[label[0]] - mmax - logf(sum));
    out[0] = (float)am;
    out[1] = loss;
  }
}

extern "C" void kernel_launch(void* const* d_in, const int* in_sizes, int n_in,
                              void* d_out, int out_size, void* d_ws, size_t ws_size,
                              hipStream_t stream) {
  const int* wid = (const int*)d_in[0];
  const int* label = (const int*)d_in[1];
  const float* emb = (const float*)d_in[2];
  const float* Ww = (const float*)d_in[3];
  const float* Wb = (const float*)d_in[4];
  const float* g = (const float*)d_in[5];
  const float* b = (const float*)d_in[6];
  const float* Pw = (const float*)d_in[7];
  const float* Pb = (const float*)d_in[8];
  float* out = (float*)d_out;

  short* h8 = (short*)d_ws;          // 256 tiles x 1024 bf16
  short* h5 = h8 + 256 * 1024;       // 32 tiles
  short* h2 = h5 + 32 * 1024;        // 4 tiles

  k_bot<<<256, 256, 0, stream>>>(wid, emb, Ww, Wb, g, b, h8);
  k_mid<<<32, 256, 0, stream>>>(wid, emb, Ww, Wb, g, b, h8, h5, 127, 63, 31);
  k_mid<<<4, 256, 0, stream>>>(wid, emb, Ww, Wb, g, b, h5, h2, 15, 7, 3);
  k_top<<<1, 256, 0, stream>>>(wid, emb, Ww, Wb, g, b, Pw, Pb, label, h2, out);
}

// Round 7
// 30.551 us; speedup vs baseline: 2.5761x; 1.0089x over previous
//
#include <hip/hip_runtime.h>
#include <hip/hip_bf16.h>

#define LN_EPS 1e-5f
#define TSB 40                 // LDS tile row stride in bf16 (80B, 16B-aligned)
#define TILEB (32 * TSB)       // shorts per tile

typedef __attribute__((ext_vector_type(8))) short bf16x8;
typedef __attribute__((ext_vector_type(16))) float f32x16;

__device__ __forceinline__ short bf16b(float f) {
  return __builtin_bit_cast(short, __float2bfloat16(f));
}

__device__ __forceinline__ void wave_reduce2(float& s1, float& s2) {
  #pragma unroll
  for (int off = 32; off; off >>= 1) {
    s1 += __shfl_xor(s1, off);
    s2 += __shfl_xor(s2, off);
  }
}

// A-frag/B-frag read from a row-major-[32][TSB] LDS tile.
// Normal tile -> A-operand (lane m holds A[m][k]); transposed tile -> B-operand.
__device__ __forceinline__ bf16x8 frag_ld(const short* t, int l, int k0) {
  return *(const bf16x8*)&t[(l & 31) * TSB + ((l >> 5) << 3) + k0];
}

__device__ __forceinline__ int cd_row(int r, int l) {
  return (r & 3) + 8 * (r >> 2) + 4 * (l >> 5);   // verified C/D mapping
}

__device__ __forceinline__ void cd_store(short* t, int l, const f32x16 d,
                                         bool transp) {
  const int col = l & 31;
  if (transp) {
    #pragma unroll
    for (int r = 0; r < 16; ++r) t[col * TSB + cd_row(r, l)] = bf16b(d[r]);
  } else {
    #pragma unroll
    for (int r = 0; r < 16; ++r) t[cd_row(r, l) * TSB + col] = bf16b(d[r]);
  }
}

struct NodeParams {
  bf16x8 w0, w1;        // Ww^T B-fragments (k0=0,16)
  float wb;             // Wb[col]
  float ga[16], be[16]; // gamma/beta at this lane's 16 C/D positions
};

__device__ __forceinline__ NodeParams load_params(const float* __restrict__ Ww,
    const float* __restrict__ Wb, const float* __restrict__ gamma,
    const float* __restrict__ beta, int l) {
  NodeParams P;
  const int n = l & 31, kh = (l >> 5) * 8;
  float w[8];
  *(float4*)&w[0] = *(const float4*)&Ww[n * 32 + kh];
  *(float4*)&w[4] = *(const float4*)&Ww[n * 32 + kh + 4];
  #pragma unroll
  for (int i = 0; i < 8; ++i) P.w0[i] = bf16b(w[i]);
  *(float4*)&w[0] = *(const float4*)&Ww[n * 32 + kh + 16];
  *(float4*)&w[4] = *(const float4*)&Ww[n * 32 + kh + 20];
  #pragma unroll
  for (int i = 0; i < 8; ++i) P.w1[i] = bf16b(w[i]);
  P.wb = Wb[n];
  #pragma unroll
  for (int r = 0; r < 16; ++r) {
    const int idx = cd_row(r, l) * 32 + n;
    P.ga[r] = gamma[idx];
    P.be[r] = beta[idx];
  }
  return P;
}

__device__ __forceinline__ f32x16 mm32(const short* A, const short* B, int l) {
  f32x16 acc = {};
  acc = __builtin_amdgcn_mfma_f32_32x32x16_bf16(frag_ld(A, l, 0),
                                                frag_ld(B, l, 0), acc, 0, 0, 0);
  acc = __builtin_amdgcn_mfma_f32_32x32x16_bf16(frag_ld(A, l, 16),
                                                frag_ld(B, l, 16), acc, 0, 0, 0);
  return acc;
}

// Full tree node on ONE wave. A = left child (normal), Bt = right child
// (transposed), Ct = emb C (transposed). T1 scratch -> A slot, T2 -> Bt slot
// (same-wave in-order LDS). Output h: fp32 to fout (root) or bf16 to dst.
__device__ __forceinline__ void node_mfma(short* A, short* Bt, const short* Ct,
                                          const NodeParams& P, int l,
                                          short* dst, bool transpOut,
                                          float* fout) {
  f32x16 t1 = mm32(A, Bt, l);
  cd_store(A, l, t1, false);            // T1 (normal) into A slot
  f32x16 t2 = mm32(A, Ct, l);
  cd_store(Bt, l, t2, false);           // T2 (normal) into Bt slot
  f32x16 x = {};
  x = __builtin_amdgcn_mfma_f32_32x32x16_bf16(frag_ld(Bt, l, 0), P.w0, x, 0, 0, 0);
  x = __builtin_amdgcn_mfma_f32_32x32x16_bf16(frag_ld(Bt, l, 16), P.w1, x, 0, 0, 0);
  float s1 = 0.f, s2 = 0.f;
  #pragma unroll
  for (int r = 0; r < 16; ++r) {
    x[r] += P.wb;
    s1 += x[r];
    s2 += x[r] * x[r];
  }
  wave_reduce2(s1, s2);
  const float mu = s1 * (1.f / 1024.f);
  const float rs = rsqrtf(s2 * (1.f / 1024.f) - mu * mu + LN_EPS);
  #pragma unroll
  for (int r = 0; r < 16; ++r)
    x[r] = fmaxf((x[r] - mu) * rs * P.ga[r] + P.be[r], 0.f);
  if (fout) {
    #pragma unroll
    for (int r = 0; r < 16; ++r) fout[cd_row(r, l) * 32 + (l & 31)] = x[r];
  } else {
    cd_store(dst, l, x, transpOut);
  }
}

// fp32 global tile [32][32] -> LDS bf16, normal or transposed; one wave
__device__ __forceinline__ void stage_f32(short* dst,
                                          const float* __restrict__ src, int l,
                                          bool transp) {
  float v[16];
  #pragma unroll
  for (int q = 0; q < 4; ++q)
    *(float4*)&v[q * 4] = *(const float4*)&src[l * 16 + q * 4];
  const int row = l >> 1, c0 = (l & 1) * 16;
  if (transp) {
    #pragma unroll
    for (int i = 0; i < 16; ++i) dst[(c0 + i) * TSB + row] = bf16b(v[i]);
  } else {
    #pragma unroll
    for (int i = 0; i < 8; ++i) {
      unsigned lo = (unsigned short)bf16b(v[2 * i]);
      unsigned hi = (unsigned short)bf16b(v[2 * i + 1]);
      ((unsigned*)dst)[row * (TSB / 2) + (c0 >> 1) + i] = lo | (hi << 16);
    }
  }
}

// bf16 global compact tile [32][32] -> LDS, normal or transposed; one wave
__device__ __forceinline__ void stage_bf16(short* dst,
                                           const short* __restrict__ src, int l,
                                           bool transp) {
  short v[16];
  *(bf16x8*)&v[0] = *(const bf16x8*)&src[l * 16];
  *(bf16x8*)&v[8] = *(const bf16x8*)&src[l * 16 + 8];
  const int row = l >> 1, c0 = (l & 1) * 16;
  if (transp) {
    #pragma unroll
    for (int i = 0; i < 16; ++i) dst[(c0 + i) * TSB + row] = v[i];
  } else {
    #pragma unroll
    for (int i = 0; i < 8; ++i) {
      unsigned lo = (unsigned short)v[2 * i];
      unsigned hi = (unsigned short)v[2 * i + 1];
      ((unsigned*)dst)[row * (TSB / 2) + (c0 >> 1) + i] = lo | (hi << 16);
    }
  }
}

// LDS normal tile -> global compact bf16 [32][32]; threads u<128, 1 b128 each
__device__ __forceinline__ void copy_out(short* __restrict__ dst, const short* t,
                                         int u) {
  if (u < 128) {
    const int row = u >> 2, c0 = (u & 3) * 8;
    *(bf16x8*)&dst[row * 32 + c0] = *(const bf16x8*)&t[row * TSB + c0];
  }
}

// leaf: load fp32 tile, LN+ReLU in-wave, write bf16 with parity layout
__device__ __forceinline__ void leaf_ln(short* dst, const float* __restrict__ src,
                                        const float* __restrict__ gamma,
                                        const float* __restrict__ beta, int l,
                                        bool transp) {
  float v[16], ga[16], be[16];
  #pragma unroll
  for (int q = 0; q < 4; ++q) {
    *(float4*)&v[q * 4] = *(const float4*)&src[l * 16 + q * 4];
    *(float4*)&ga[q * 4] = *(const float4*)&gamma[l * 16 + q * 4];
    *(float4*)&be[q * 4] = *(const float4*)&beta[l * 16 + q * 4];
  }
  float s1 = 0.f, s2 = 0.f;
  #pragma unroll
  for (int i = 0; i < 16; ++i) { s1 += v[i]; s2 += v[i] * v[i]; }
  wave_reduce2(s1, s2);
  const float mu = s1 * (1.f / 1024.f);
  const float rs = rsqrtf(s2 * (1.f / 1024.f) - mu * mu + LN_EPS);
  #pragma unroll
  for (int i = 0; i < 16; ++i)
    v[i] = fmaxf((v[i] - mu) * rs * ga[i] + be[i], 0.f);
  const int row = l >> 1, c0 = (l & 1) * 16;
  if (transp) {
    #pragma unroll
    for (int i = 0; i < 16; ++i) dst[(c0 + i) * TSB + row] = bf16b(v[i]);
  } else {
    #pragma unroll
    for (int i = 0; i < 8; ++i) {
      unsigned lo = (unsigned short)bf16b(v[2 * i]);
      unsigned hi = (unsigned short)bf16b(v[2 * i + 1]);
      ((unsigned*)dst)[row * (TSB / 2) + (c0 >> 1) + i] = lo | (hi << 16);
    }
  }
}

// ---- K1: 8 leaves + 4xL9 + 2xL8 + 1xL7; 128 blocks x 512 thr ----
__global__ __launch_bounds__(512) void k_bot7(
    const int* __restrict__ wid, const float* __restrict__ emb,
    const float* __restrict__ Ww, const float* __restrict__ Wb,
    const float* __restrict__ gamma, const float* __restrict__ beta,
    short* __restrict__ h7) {
  __shared__ __align__(16) short pool[15 * TILEB];
  const int u = threadIdx.x, blk = blockIdx.x;
  const int wv = u >> 6, l = u & 63;
  NodeParams P = load_params(Ww, Wb, gamma, beta, l);
  // C tiles (transposed, B-operands): L9 -> 8..11, L8 -> 12..13, L7 -> 14
  if (wv < 4)
    stage_f32(pool + (8 + wv) * TILEB,
              emb + (size_t)wid[511 + 4 * blk + wv] * 1024, l, true);
  else if (wv < 6)
    stage_f32(pool + (8 + wv) * TILEB,
              emb + (size_t)wid[255 + 2 * blk + (wv - 4)] * 1024, l, true);
  else if (wv == 6)
    stage_f32(pool + 14 * TILEB, emb + (size_t)wid[127 + blk] * 1024, l, true);
  // leaves: one per wave -> slots 0..7; odd position = right = transposed
  leaf_ln(pool + wv * TILEB, emb + (size_t)wid[1023 + 8 * blk + wv] * 1024,
          gamma, beta, l, (wv & 1) != 0);
  __syncthreads();
  // L9: 4 nodes on waves 0..3; out -> C slot, parity by node index
  if (wv < 4)
    node_mfma(pool + 2 * wv * TILEB, pool + (2 * wv + 1) * TILEB,
              pool + (8 + wv) * TILEB, P, l, pool + (8 + wv) * TILEB,
              (wv & 1) != 0, nullptr);
  __syncthreads();
  // L8: 2 nodes on waves 0,1
  if (wv < 2)
    node_mfma(pool + (8 + 2 * wv) * TILEB, pool + (9 + 2 * wv) * TILEB,
              pool + (12 + wv) * TILEB, P, l, pool + (12 + wv) * TILEB,
              (wv & 1) != 0, nullptr);
  __syncthreads();
  // L7: 1 node on wave 0, out normal -> slot 14
  if (wv == 0)
    node_mfma(pool + 12 * TILEB, pool + 13 * TILEB, pool + 14 * TILEB, P, l,
              pool + 14 * TILEB, false, nullptr);
  __syncthreads();
  copy_out(h7 + (size_t)blk * 1024, pool + 14 * TILEB, u);
}

// ---- K2: L6 + L5 + L4; 16 blocks x 512 thr ----
__global__ __launch_bounds__(512) void k_mid16(
    const int* __restrict__ wid, const float* __restrict__ emb,
    const float* __restrict__ Ww, const float* __restrict__ Wb,
    const float* __restrict__ gamma, const float* __restrict__ beta,
    const short* __restrict__ hin, short* __restrict__ hout) {
  __shared__ __align__(16) short pool[15 * TILEB];
  const int u = threadIdx.x, blk = blockIdx.x;
  const int wv = u >> 6, l = u & 63;
  NodeParams P = load_params(Ww, Wb, gamma, beta, l);
  // children: wave w stages h7 tile 8*blk+w -> slot w, parity by position
  stage_bf16(pool + wv * TILEB, hin + (size_t)(8 * blk + wv) * 1024, l,
             (wv & 1) != 0);
  // C tiles: L6 (base 63) -> 8..11, L5 (base 31) -> 12..13, L4 (base 15) -> 14
  if (wv < 4)
    stage_f32(pool + (8 + wv) * TILEB,
              emb + (size_t)wid[63 + 4 * blk + wv] * 1024, l, true);
  else if (wv < 6)
    stage_f32(pool + (8 + wv) * TILEB,
              emb + (size_t)wid[31 + 2 * blk + (wv - 4)] * 1024, l, true);
  else if (wv == 6)
    stage_f32(pool + 14 * TILEB, emb + (size_t)wid[15 + blk] * 1024, l, true);
  __syncthreads();
  // L6: 4 nodes on waves 0..3
  if (wv < 4)
    node_mfma(pool + 2 * wv * TILEB, pool + (2 * wv + 1) * TILEB,
              pool + (8 + wv) * TILEB, P, l, pool + (8 + wv) * TILEB,
              (wv & 1) != 0, nullptr);
  __syncthreads();
  // L5: 2 nodes on waves 0,1
  if (wv < 2)
    node_mfma(pool + (8 + 2 * wv) * TILEB, pool + (9 + 2 * wv) * TILEB,
              pool + (12 + wv) * TILEB, P, l, pool + (12 + wv) * TILEB,
              (wv & 1) != 0, nullptr);
  __syncthreads();
  // L4: 1 node on wave 0, out normal -> slot 14
  if (wv == 0)
    node_mfma(pool + 12 * TILEB, pool + 13 * TILEB, pool + 14 * TILEB, P, l,
              pool + 14 * TILEB, false, nullptr);
  __syncthreads();
  copy_out(hout + (size_t)blk * 1024, pool + 14 * TILEB, u);
}

// ---- K3: L3 + L2 + L1 + L0 + head; 1 block x 512 thr ----
__global__ __launch_bounds__(512) void k_top2(
    const int* __restrict__ wid, const float* __restrict__ emb,
    const float* __restrict__ Ww, const float* __restrict__ Wb,
    const float* __restrict__ gamma, const float* __restrict__ beta,
    const float* __restrict__ Pw, const float* __restrict__ Pb,
    const int* __restrict__ label, const short* __restrict__ hin,
    float* __restrict__ out) {
  __shared__ __align__(16) short pool[31 * TILEB];
  __shared__ float rootf[1024];
  __shared__ float lred[10];
  const int u = threadIdx.x;
  const int wv = u >> 6, l = u & 63;
  NodeParams P = load_params(Ww, Wb, gamma, beta, l);
  // children: wave w stages h4 tiles 2w (left, normal) and 2w+1 (right, transp)
  stage_bf16(pool + 2 * wv * TILEB, hin + (size_t)(2 * wv) * 1024, l, false);
  stage_bf16(pool + (2 * wv + 1) * TILEB, hin + (size_t)(2 * wv + 1) * 1024, l,
             true);
  // C tiles: L3 (base 7) -> 16..23, L2 (base 3) -> 24..27,
  //          L1 (base 1) -> 28..29, L0 (wid[0]) -> 30
  stage_f32(pool + (16 + wv) * TILEB, emb + (size_t)wid[7 + wv] * 1024, l, true);
  if (wv < 4)
    stage_f32(pool + (24 + wv) * TILEB, emb + (size_t)wid[3 + wv] * 1024, l, true);
  else if (wv < 6)
    stage_f32(pool + (24 + wv) * TILEB,
              emb + (size_t)wid[1 + (wv - 4)] * 1024, l, true);
  else if (wv == 6)
    stage_f32(pool + 30 * TILEB, emb + (size_t)wid[0] * 1024, l, true);
  __syncthreads();
  // L3: 8 nodes, one per wave
  node_mfma(pool + 2 * wv * TILEB, pool + (2 * wv + 1) * TILEB,
            pool + (16 + wv) * TILEB, P, l, pool + (16 + wv) * TILEB,
            (wv & 1) != 0, nullptr);
  __syncthreads();
  // L2: 4 nodes on waves 0..3
  if (wv < 4)
    node_mfma(pool + (16 + 2 * wv) * TILEB, pool + (17 + 2 * wv) * TILEB,
              pool + (24 + wv) * TILEB, P, l, pool + (24 + wv) * TILEB,
              (wv & 1) != 0, nullptr);
  __syncthreads();
  // L1: 2 nodes on waves 0,1
  if (wv < 2)
    node_mfma(pool + (24 + 2 * wv) * TILEB, pool + (25 + 2 * wv) * TILEB,
              pool + (28 + wv) * TILEB, P, l, pool + (28 + wv) * TILEB,
              (wv & 1) != 0, nullptr);
  __syncthreads();
  // L0 -> fp32 root
  if (wv == 0)
    node_mfma(pool + 28 * TILEB, pool + 29 * TILEB, pool + 30 * TILEB, P, l,
              nullptr, false, rootf);
  __syncthreads();
  // head: wave wv handles classes wv and wv+8
  #pragma unroll
  for (int q = 0; q < 2; ++q) {
    const int c = wv + 8 * q;
    if (c < 10) {
      float p = 0.f;
      #pragma unroll
      for (int t = 0; t < 4; ++t) {
        float4 r4 = *(const float4*)&rootf[l * 16 + t * 4];
        float4 w4 = *(const float4*)&Pw[c * 1024 + l * 16 + t * 4];
        p += r4.x * w4.x + r4.y * w4.y + r4.z * w4.z + r4.w * w4.w;
      }
      #pragma unroll
      for (int off = 32; off; off >>= 1) p += __shfl_xor(p, off);
      if (l == 0) lred[c] = p + Pb[c];
    }
  }
  __syncthreads();
  if (u == 0) {
    float mmax = lred[0];
    int am = 0;
    #pragma unroll
    for (int c = 1; c < 10; ++c)
      if (lred[c] > mmax) { mmax = lred[c]; am = c; }
    float sum = 0.f;
    #pragma unroll
    for (int c = 0; c < 10; ++c) sum += expf(lred[c] - mmax);
    const float loss = -(lred[label[0]] - mmax - logf(sum));
    out[0] = (float)am;
    out[1] = loss;
  }
}

extern "C" void kernel_launch(void* const* d_in, const int* in_sizes, int n_in,
                              void* d_out, int out_size, void* d_ws, size_t ws_size,
                              hipStream_t stream) {
  const int* wid = (const int*)d_in[0];
  const int* label = (const int*)d_in[1];
  const float* emb = (const float*)d_in[2];
  const float* Ww = (const float*)d_in[3];
  const float* Wb = (const float*)d_in[4];
  const float* g = (const float*)d_in[5];
  const float* b = (const float*)d_in[6];
  const float* Pw = (const float*)d_in[7];
  const float* Pb = (const float*)d_in[8];
  float* out = (float*)d_out;

  short* h7 = (short*)d_ws;          // 128 tiles x 1024 bf16
  short* h4 = h7 + 128 * 1024;       // 16 tiles

  k_bot7<<<128, 512, 0, stream>>>(wid, emb, Ww, Wb, g, b, h7);
  k_mid16<<<16, 512, 0, stream>>>(wid, emb, Ww, Wb, g, b, h7, h4);
  k_top2<<<1, 512, 0, stream>>>(wid, emb, Ww, Wb, g, b, Pw, Pb, label, h4, out);
}